// Round 18
// baseline (287.995 us; speedup 1.0000x reference)
//
#include <hip/hip_runtime.h>

#define T_DIM 2048
#define B_DIM 4
#define S_DIM 2048
#define E_DIM 1024
#define H_NUM 16
#define HD    64
#define NH    64      // B*H
#define SP1   2049    // S+1 (bias token appended)
#define SPAD  2112    // 33*64, padded key length
#define NCHUNK 33
#define NTOKE ((size_t)T_DIM * B_DIM * E_DIM)   // 8192*1024

typedef short bf16x8 __attribute__((ext_vector_type(8)));
typedef short bf16x4 __attribute__((ext_vector_type(4)));
typedef float f32x4  __attribute__((ext_vector_type(4)));
typedef float f32x16 __attribute__((ext_vector_type(16)));
typedef unsigned int u32;

// log2(e): softmax done in exp2 domain; folded into Q projection scale.
#define QSCALE 0.18033688011112042f   // 0.125 * log2(e)

#if __has_builtin(__builtin_amdgcn_exp2f)
__device__ __forceinline__ float exp2_fast(float x) { return __builtin_amdgcn_exp2f(x); }
#else
__device__ __forceinline__ float exp2_fast(float x) { return __expf(x * 0.6931471805599453f); }
#endif

__device__ __forceinline__ unsigned short f2bf(float x) {
    union { float f; unsigned int u; } v; v.f = x;
    unsigned int r = v.u + 0x7FFFu + ((v.u >> 16) & 1u);   // RNE
    return (unsigned short)(r >> 16);
}

__device__ __forceinline__ u32 cvtpk_bf16(float lo, float hi) {
    u32 r;
    asm("v_cvt_pk_bf16_f32 %0, %1, %2" : "=v"(r) : "v"(lo), "v"(hi));
    return r;
}
__device__ __forceinline__ void plswap(u32& a, u32& b) {
    asm("v_permlane32_swap_b32 %0, %1" : "+v"(a), "+v"(b));
}
__device__ __forceinline__ float max3f(float a, float b, float c) {
    float d;
    asm("v_max3_f32 %0, %1, %2, %3" : "=v"(d) : "v"(a), "v"(b), "v"(c));
    return d;
}

// async global->LDS, 16B per lane (m97 staging primitive)
__device__ __forceinline__ void load_lds16(const void* g, void* l) {
    __builtin_amdgcn_global_load_lds(
        (const __attribute__((address_space(1))) unsigned int*)g,
        (__attribute__((address_space(3))) unsigned int*)l, 16, 0, 0);
}

// ---------------------------------------------------------------------------
// One launch: y=0..2 inputs q|k|v -> bf16; y=3 weights + kv pad fill.
// ---------------------------------------------------------------------------
__global__ __launch_bounds__(256)
void cvt_all(const float* __restrict__ q, const float* __restrict__ k,
             const float* __restrict__ v, const float* __restrict__ w0,
             const float* __restrict__ w1, const float* __restrict__ w2,
             const float* __restrict__ w3, short* __restrict__ indst,
             short* __restrict__ wdst, short* __restrict__ k_h,
             short* __restrict__ v_h, const float* __restrict__ bias_k,
             const float* __restrict__ bias_v)
{
    const int y = blockIdx.y;
    if (y < 3) {
        const float* src = (y == 0) ? q : (y == 1) ? k : v;
        short* d = indst + (size_t)y * NTOKE;
        const size_t i = (size_t)blockIdx.x * 256 + threadIdx.x;
        const float4* s = reinterpret_cast<const float4*>(src) + i * 2;
        float4 a = s[0], b = s[1];
        uint4 o;
        o.x = cvtpk_bf16(a.x, a.y); o.y = cvtpk_bf16(a.z, a.w);
        o.z = cvtpk_bf16(b.x, b.y); o.w = cvtpk_bf16(b.z, b.w);
        *(reinterpret_cast<uint4*>(d) + i) = o;
    } else {
        const size_t gi = (size_t)blockIdx.x * 256 + threadIdx.x;
        const size_t per = (size_t)E_DIM * E_DIM / 8;              // 131072
        if (gi < 4 * per) {
            const int wsel = (int)(gi / per);
            const size_t i = gi % per;
            const float* src = (wsel == 0) ? w0 : (wsel == 1) ? w1 : (wsel == 2) ? w2 : w3;
            short* d = wdst + (size_t)wsel * E_DIM * E_DIM;
            const float4* s = reinterpret_cast<const float4*>(src) + i * 2;
            float4 a = s[0], b = s[1];
            uint4 o;
            o.x = cvtpk_bf16(a.x, a.y); o.y = cvtpk_bf16(a.z, a.w);
            o.z = cvtpk_bf16(b.x, b.y); o.w = cvtpk_bf16(b.z, b.w);
            *(reinterpret_cast<uint4*>(d) + i) = o;
        } else {
            const size_t fi = gi - 4 * per;                        // kv pad fill
            if (fi < (size_t)(SPAD - S_DIM) * NH * HD) {
                const int d   = (int)(fi & 63);
                const int row = (int)((fi >> 6) & 63);
                const int n   = (int)(fi >> 12);
                short bk = 0, bv = 0;
                if (row == 0) {
                    bk = (short)f2bf(bias_k[(n & 15) * HD + d]);
                    bv = (short)f2bf(bias_v[(n & 15) * HD + d]);
                }
                const size_t idx = ((size_t)n * SPAD + S_DIM + row) * HD + d;
                k_h[idx] = bk;
                v_h[idx] = bv;
            }
        }
    }
}

// ---------------------------------------------------------------------------
// QKV GEMM: BM=256 x BN=128 tile, 512 threads (8 waves, 4x2), BK=64,
// single-buffered 48 KB, 2-barrier m97 loop. 32 MFMA per barrier (2x round-17)
// against the same fixed stall -> higher efficiency. XCD-banded 1D grid 768.
// ---------------------------------------------------------------------------
__global__ __launch_bounds__(512, 4)
void gemm_qkv(const short* __restrict__ Abase, const short* __restrict__ Wall,
              const float* __restrict__ biasAll, short* __restrict__ outp)
{
    __shared__ short As[256][64];
    __shared__ short Bs[128][64];

    const int id = blockIdx.x;                 // 0..767
    const int xcd = id & 7;
    const int j = id >> 3;                     // 0..95
    const int z = j >> 5;                      // 0..2
    const int jj = j & 31;                     // 0..31
    const int bm = xcd * 4 + (jj & 3);         // 4 bm-tiles per XCD (2 MB band)
    const int bn = jj >> 2;                    // 0..7

    const short* Az = Abase + (size_t)z * NTOKE;
    const short* W  = Wall + (size_t)z * E_DIM * E_DIM;
    const float* bias = biasAll + z * E_DIM;

    const int tid = threadIdx.x;
    const int l = tid & 63, w = tid >> 6;      // w 0..7
    const int wr = w >> 1, wc = w & 1;         // wr 0..3, wc 0..1
    const int lr = l & 15, lg = l >> 4;
    const int srow = tid >> 3, scol = (tid & 7) * 8;   // 64 rows / 512 threads

    f32x4 acc[4][4] = {};

    for (int k0 = 0; k0 < E_DIM; k0 += 64) {
        // stage A (256 rows) + W (128 rows): 6 loads/thread
#pragma unroll
        for (int r = 0; r < 4; ++r) {
            const int row = r * 64 + srow;
            load_lds16(Az + (size_t)(bm * 256 + row) * E_DIM + k0 + scol, &As[row][scol]);
        }
#pragma unroll
        for (int r = 0; r < 2; ++r) {
            const int row = r * 64 + srow;
            load_lds16(W + (size_t)(bn * 128 + row) * E_DIM + k0 + scol, &Bs[row][scol]);
        }
        __syncthreads();

        __builtin_amdgcn_s_setprio(1);
#pragma unroll
        for (int c = 0; c < 2; ++c) {
            bf16x8 af[4], bf[4];
#pragma unroll
            for (int mi = 0; mi < 4; ++mi)
                af[mi] = *reinterpret_cast<const bf16x8*>(&As[wr * 64 + mi * 16 + lr][c * 32 + lg * 8]);
#pragma unroll
            for (int ni = 0; ni < 4; ++ni)
                bf[ni] = *reinterpret_cast<const bf16x8*>(&Bs[wc * 64 + ni * 16 + lr][c * 32 + lg * 8]);
#pragma unroll
            for (int mi = 0; mi < 4; ++mi)
#pragma unroll
                for (int ni = 0; ni < 4; ++ni)
                    acc[mi][ni] = __builtin_amdgcn_mfma_f32_16x16x32_bf16(
                        af[mi], bf[ni], acc[mi][ni], 0, 0, 0);
        }
        __builtin_amdgcn_s_setprio(0);
        __syncthreads();
    }

#pragma unroll
    for (int mi = 0; mi < 4; ++mi)
#pragma unroll
        for (int ni = 0; ni < 4; ++ni) {
            const int colg = bn * 128 + wc * 64 + ni * 16 + lr;
            const float bv = bias[colg];
#pragma unroll
            for (int r = 0; r < 4; ++r) {
                const int m = bm * 256 + wr * 64 + mi * 16 + lg * 4 + r;
                float v = acc[mi][ni][r] + bv;
                if (z == 0) v *= QSCALE;
                const int seq = m >> 2, b = m & 3;
                const int head = colg >> 6, d = colg & 63;
                const int sd = (z == 0) ? T_DIM : SPAD;
                short* ob = outp;
                if (z == 1) ob += (size_t)NH * T_DIM * HD;
                else if (z == 2) ob += (size_t)NH * T_DIM * HD + (size_t)NH * SPAD * HD;
                ob[((size_t)(b * 16 + head) * sd + seq) * HD + d] = (short)f2bf(v);
            }
        }
}

// ---------------------------------------------------------------------------
// Out-proj GEMM: 2-phase dbuf BK=64 + XCD-banded grid (round-17 form).
// ---------------------------------------------------------------------------
__global__ __launch_bounds__(256, 2)
void gemm_out(const short* __restrict__ o_h, const short* __restrict__ wob,
              const float* __restrict__ out_b, float* __restrict__ out)
{
    __shared__ short As[2][128][64];
    __shared__ short Bs[2][128][64];

    const int id = blockIdx.x;                 // 0..511
    const int xcd = id & 7;
    const int j = id >> 3;                     // 0..63
    const int bm = xcd * 8 + (j & 7);
    const int bn = j >> 3;

    const int tid = threadIdx.x;
    const int l = tid & 63, w = tid >> 6;
    const int wr = w >> 1, wc = w & 1;
    const int lr = l & 15, lg = l >> 4;
    const int srow = tid >> 3, scol = (tid & 7) * 8;

    auto stage = [&](int b, int k0) {
#pragma unroll
        for (int r = 0; r < 4; ++r) {
            const int row = r * 32 + srow;
            const int m = bm * 128 + row;
            const short* ga = o_h +
                ((size_t)((m & 3) * 16 + (k0 >> 6)) * T_DIM + (m >> 2)) * HD + scol;
            load_lds16(ga, &As[b][row][scol]);
            load_lds16(wob + (size_t)(bn * 128 + row) * E_DIM + k0 + scol, &Bs[b][row][scol]);
        }
    };

    stage(0, 0);
    __syncthreads();

    f32x4 acc[4][4] = {};
    int buf = 0;

    for (int k0 = 0; k0 < E_DIM; k0 += 64) {
        if (k0 + 64 < E_DIM) stage(buf ^ 1, k0 + 64);

        __builtin_amdgcn_s_setprio(1);
#pragma unroll
        for (int c = 0; c < 2; ++c) {
            bf16x8 af[4], bf[4];
#pragma unroll
            for (int mi = 0; mi < 4; ++mi)
                af[mi] = *reinterpret_cast<const bf16x8*>(&As[buf][wr * 64 + mi * 16 + lr][c * 32 + lg * 8]);
#pragma unroll
            for (int ni = 0; ni < 4; ++ni)
                bf[ni] = *reinterpret_cast<const bf16x8*>(&Bs[buf][wc * 64 + ni * 16 + lr][c * 32 + lg * 8]);
#pragma unroll
            for (int mi = 0; mi < 4; ++mi)
#pragma unroll
                for (int ni = 0; ni < 4; ++ni)
                    acc[mi][ni] = __builtin_amdgcn_mfma_f32_16x16x32_bf16(
                        af[mi], bf[ni], acc[mi][ni], 0, 0, 0);
        }
        __builtin_amdgcn_s_setprio(0);
        __syncthreads();
        buf ^= 1;
    }

#pragma unroll
    for (int mi = 0; mi < 4; ++mi)
#pragma unroll
        for (int ni = 0; ni < 4; ++ni) {
            const int colg = bn * 128 + wc * 64 + ni * 16 + lr;
            const float bv = out_b[colg];
#pragma unroll
            for (int r = 0; r < 4; ++r) {
                const int m = bm * 128 + wr * 64 + mi * 16 + lg * 4 + r;
                out[(size_t)m * E_DIM + colg] = acc[mi][ni][r] + bv;
            }
        }
}

// ---------------------------------------------------------------------------
// Swapped 32x32 MFMA flash attention (round-17 form, unchanged).
// ---------------------------------------------------------------------------
__global__ __launch_bounds__(512, 4)
void attn_mfma(const short* __restrict__ q_h, const short* __restrict__ k_h,
               const short* __restrict__ v_h, short* __restrict__ o_h,
               float* __restrict__ m_arr, float* __restrict__ l_arr)
{
    __shared__ short KsD[2][64 * 64];
    __shared__ short VtD[2][64 * 64];

    const int id = blockIdx.x;
    const int xcd = id & 7, slot = id >> 3;        // slot 0..63
    const int n = xcd * 8 + (slot >> 3);
    const int q0 = (slot & 7) * 256;

    const int tid = threadIdx.x, l = tid & 63, w = tid >> 6;   // w 0..7
    const int ql = l & 31;
    const int hi = l >> 5;
    const int qrow = q0 + w * 32 + ql;

    const int krow = tid >> 3, kcg = tid & 7;
    const int kswz = (kcg * 16) ^ ((krow & 7) << 4);
    const int sp = tid & 31, dq = tid >> 5;

    const short* kbase = k_h + (size_t)n * SPAD * HD;
    const short* vbase = v_h + (size_t)n * SPAD * HD;

    bf16x8 aq0, aq1, aq2, aq3;
    {
        const short* qp = q_h + ((size_t)n * T_DIM + qrow) * HD + hi * 8;
        aq0 = *(const bf16x8*)(qp);
        aq1 = *(const bf16x8*)(qp + 16);
        aq2 = *(const bf16x8*)(qp + 32);
        aq3 = *(const bf16x8*)(qp + 48);
    }

    bf16x8 pk  = *(const bf16x8*)(kbase + (size_t)krow * HD + kcg * 8);
    bf16x4 pva = *(const bf16x4*)(vbase + (size_t)(2 * sp) * HD + dq * 4);
    bf16x4 pvb = *(const bf16x4*)(vbase + (size_t)(2 * sp + 1) * HD + dq * 4);
    {
        char* KsB = (char*)KsD[0];
        char* VtB = (char*)VtD[0];
        *(bf16x8*)(KsB + krow * 128 + kswz) = pk;
#pragma unroll
        for (int j = 0; j < 4; ++j) {
            u32 pkd = (u32)(unsigned short)pva[j] | ((u32)(unsigned short)pvb[j] << 16);
            const int d = dq * 4 + j;
            *(u32*)(VtB + d * 128 + ((4 * sp) ^ ((d & 7) << 4))) = pkd;
        }
    }
    __syncthreads();

    float m_run = 0.0f;
    float l_run = 0.0f;
    f32x16 accA, accB;
#pragma unroll
    for (int r = 0; r < 16; ++r) { accA[r] = 0.f; accB[r] = 0.f; }

    for (int kc = 0; kc < NCHUNK; ++kc) {
        const char* KsB = (const char*)KsD[kc & 1];
        const char* VtB = (const char*)VtD[kc & 1];
        const bool more = (kc + 1 < NCHUNK);

        if (more) {
            const int s0n = (kc + 1) * 64;
            pk  = *(const bf16x8*)(kbase + (size_t)(s0n + krow) * HD + kcg * 8);
            pva = *(const bf16x4*)(vbase + (size_t)(s0n + 2 * sp) * HD + dq * 4);
            pvb = *(const bf16x4*)(vbase + (size_t)(s0n + 2 * sp + 1) * HD + dq * 4);
        }

        f32x16 sc0, sc1;
        const float nm = -m_run;
#pragma unroll
        for (int r = 0; r < 16; ++r) { sc0[r] = nm; sc1[r] = nm; }
        __builtin_amdgcn_s_setprio(1);
#pragma unroll
        for (int sl = 0; sl < 4; ++sl) {
            const int cb = ((sl * 32) + hi * 16) ^ ((ql & 7) << 4);
            bf16x8 kf0 = *(const bf16x8*)(KsB + ql * 128 + cb);
            bf16x8 kf1 = *(const bf16x8*)(KsB + (32 + ql) * 128 + cb);
            bf16x8 qf = (sl == 0) ? aq0 : (sl == 1) ? aq1 : (sl == 2) ? aq2 : aq3;
            sc0 = __builtin_amdgcn_mfma_f32_32x32x16_bf16(kf0, qf, sc0, 0, 0, 0);
            sc1 = __builtin_amdgcn_mfma_f32_32x32x16_bf16(kf1, qf, sc1, 0, 0, 0);
        }
        __builtin_amdgcn_s_setprio(0);

        const int s0 = kc * 64;
        if (s0 + 64 > SP1) {
#pragma unroll
            for (int r = 0; r < 16; ++r) {
                const int key = (r & 3) + 8 * (r >> 2) + 4 * hi;
                if (s0 + key >= SP1)      sc0[r] = -1e30f;
                if (s0 + 32 + key >= SP1) sc1[r] = -1e30f;
            }
        }

        // ---- max reduce via v_max3 ----
        float a0 = max3f(sc0[0],  sc0[1],  sc0[2]);
        float a1 = max3f(sc0[3],  sc0[4],  sc0[5]);
        float a2 = max3f(sc0[6],  sc0[7],  sc0[8]);
        float a3 = max3f(sc0[9],  sc0[10], sc0[11]);
        float a4 = max3f(sc0[12], sc0[13], sc0[14]);
        float a5 = max3f(sc0[15], sc1[0],  sc1[1]);
        float a6 = max3f(sc1[2],  sc1[3],  sc1[4]);
        float a7 = max3f(sc1[5],  sc1[6],  sc1[7]);
        float a8 = max3f(sc1[8],  sc1[9],  sc1[10]);
        float a9 = max3f(sc1[11], sc1[12], sc1[13]);
        float aA = fmaxf(sc1[14], sc1[15]);
        float b0 = max3f(a0, a1, a2);
        float b1 = max3f(a3, a4, a5);
        float b2 = max3f(a6, a7, a8);
        float b3 = fmaxf(a9, aA);
        float mxl = fmaxf(max3f(b0, b1, b2), b3);
        const float mx = fmaxf(mxl, __shfl_xor(mxl, 32));
        if (!__all(mx <= 8.0f)) {
            const float sh = fmaxf(mx, 0.0f);
            const float fac = exp2_fast(-sh);
            l_run *= fac;
#pragma unroll
            for (int r = 0; r < 16; ++r) {
                accA[r] *= fac; accB[r] *= fac;
                sc0[r] -= sh;   sc1[r] -= sh;
            }
            m_run += sh;
        }
        float p0[16], p1[16];
#pragma unroll
        for (int r = 0; r < 16; ++r) p0[r] = exp2_fast(sc0[r]);
#pragma unroll
        for (int r = 0; r < 16; ++r) p1[r] = exp2_fast(sc1[r]);
        float sv[16];
#pragma unroll
        for (int r = 0; r < 16; ++r) sv[r] = p0[r] + p1[r];
#pragma unroll
        for (int s = 8; s > 0; s >>= 1)
#pragma unroll
            for (int r = 0; r < s; ++r) sv[r] += sv[r + s];
        l_run += sv[0] + __shfl_xor(sv[0], 32);

        union PF { u32 u[4]; bf16x8 v; };
        PF pf0, pf1, pf2, pf3;
        {
            u32 a0_ = cvtpk_bf16(p0[0], p0[1]),   b0_ = cvtpk_bf16(p0[4], p0[5]);   plswap(a0_, b0_);
            u32 a1_ = cvtpk_bf16(p0[2], p0[3]),   b1_ = cvtpk_bf16(p0[6], p0[7]);   plswap(a1_, b1_);
            u32 a2_ = cvtpk_bf16(p0[8], p0[9]),   b2_ = cvtpk_bf16(p0[12], p0[13]); plswap(a2_, b2_);
            u32 a3_ = cvtpk_bf16(p0[10], p0[11]), b3_ = cvtpk_bf16(p0[14], p0[15]); plswap(a3_, b3_);
            pf0.u[0] = a0_; pf0.u[1] = a1_; pf0.u[2] = b0_; pf0.u[3] = b1_;
            pf1.u[0] = a2_; pf1.u[1] = a3_; pf1.u[2] = b2_; pf1.u[3] = b3_;
            u32 c0_ = cvtpk_bf16(p1[0], p1[1]),   d0_ = cvtpk_bf16(p1[4], p1[5]);   plswap(c0_, d0_);
            u32 c1_ = cvtpk_bf16(p1[2], p1[3]),   d1_ = cvtpk_bf16(p1[6], p1[7]);   plswap(c1_, d1_);
            u32 c2_ = cvtpk_bf16(p1[8], p1[9]),   d2_ = cvtpk_bf16(p1[12], p1[13]); plswap(c2_, d2_);
            u32 c3_ = cvtpk_bf16(p1[10], p1[11]), d3_ = cvtpk_bf16(p1[14], p1[15]); plswap(c3_, d3_);
            pf2.u[0] = c0_; pf2.u[1] = c1_; pf2.u[2] = d0_; pf2.u[3] = d1_;
            pf3.u[0] = c2_; pf3.u[1] = c3_; pf3.u[2] = d2_; pf3.u[3] = d3_;
        }

        __builtin_amdgcn_s_setprio(1);
#pragma unroll
        for (int ksl = 0; ksl < 4; ++ksl) {
            const int cb = ((ksl * 32) + hi * 16) ^ ((ql & 7) << 4);
            bf16x8 vf0 = *(const bf16x8*)(VtB + ql * 128 + cb);
            bf16x8 vf1 = *(const bf16x8*)(VtB + (32 + ql) * 128 + cb);
            const bf16x8 pv = (ksl == 0) ? pf0.v : (ksl == 1) ? pf1.v : (ksl == 2) ? pf2.v : pf3.v;
            accA = __builtin_amdgcn_mfma_f32_32x32x16_bf16(vf0, pv, accA, 0, 0, 0);
            accB = __builtin_amdgcn_mfma_f32_32x32x16_bf16(vf1, pv, accB, 0, 0, 0);
        }
        __builtin_amdgcn_s_setprio(0);

        if (more) {
            char* KsN = (char*)KsD[(kc & 1) ^ 1];
            char* VtN = (char*)VtD[(kc & 1) ^ 1];
            *(bf16x8*)(KsN + krow * 128 + kswz) = pk;
#pragma unroll
            for (int j = 0; j < 4; ++j) {
                u32 pkd = (u32)(unsigned short)pva[j] | ((u32)(unsigned short)pvb[j] << 16);
                const int d = dq * 4 + j;
                *(u32*)(VtN + d * 128 + ((4 * sp) ^ ((d & 7) << 4))) = pkd;
            }
            __syncthreads();
        }
    }

    const float il = 1.0f / l_run;
    short* orow = o_h + ((size_t)n * T_DIM + qrow) * HD;
#pragma unroll
    for (int rq = 0; rq < 4; ++rq) {
        uint2 st;
        st.x = cvtpk_bf16(accA[rq * 4 + 0] * il, accA[rq * 4 + 1] * il);
        st.y = cvtpk_bf16(accA[rq * 4 + 2] * il, accA[rq * 4 + 3] * il);
        *(uint2*)(orow + rq * 8 + hi * 4) = st;
        uint2 st2;
        st2.x = cvtpk_bf16(accB[rq * 4 + 0] * il, accB[rq * 4 + 1] * il);
        st2.y = cvtpk_bf16(accB[rq * 4 + 2] * il, accB[rq * 4 + 3] * il);
        *(uint2*)(orow + 32 + rq * 8 + hi * 4) = st2;
    }
    if (hi == 0) {
        m_arr[n * T_DIM + qrow] = m_run;
        l_arr[n * T_DIM + qrow] = l_run;
    }
}

// ---------------------------------------------------------------------------
// avg_weights: standalone, -mq in acc init (unchanged).
// ---------------------------------------------------------------------------
__global__ __launch_bounds__(256)
void colsum_mfma(const short* __restrict__ q_h, const short* __restrict__ k_h,
                 const float* __restrict__ m_arr, const float* __restrict__ l_arr,
                 float* __restrict__ avg_out)
{
    __shared__ short Qs[2][64][72];
    __shared__ float msh[2][64];
    __shared__ float lih[2][64];

    const int id = blockIdx.x;
    const int xcd = id & 7, slot = id >> 3;        // slot 0..263
    const int n = xcd * 8 + slot / 33;
    const int s0 = (slot % 33) * 64;

    const int tid = threadIdx.x, l = tid & 63, w = tid >> 6;
    const int lr = l & 15, lg = l >> 4;
    const int qr = tid >> 3, qcg = tid & 7;

    const short* qbase = q_h + (size_t)n * T_DIM * HD;

    bf16x8 ak[2];
#pragma unroll
    for (int c = 0; c < 2; ++c)
        ak[c] = *reinterpret_cast<const bf16x8*>(
            k_h + ((size_t)n * SPAD + s0 + w * 16 + lr) * HD + c * 32 + lg * 8);

    bf16x8 qa = *(const bf16x8*)(qbase + (size_t)qr * HD + qcg * 8);
    bf16x8 qb = *(const bf16x8*)(qbase + (size_t)(32 + qr) * HD + qcg * 8);
    float mlv = 0.f;
    if (tid < 64) mlv = m_arr[n * T_DIM + tid];
    else if (tid < 128) mlv = l_arr[n * T_DIM + tid - 64];
    *(bf16x8*)&Qs[0][qr][qcg * 8] = qa;
    *(bf16x8*)&Qs[0][32 + qr][qcg * 8] = qb;
    if (tid < 64) msh[0][tid] = mlv;
    else if (tid < 128) lih[0][tid - 64] = 1.0f / mlv;
    __syncthreads();

    float csum[4] = {0.f, 0.f, 0.f, 0.f};

    for (int it = 0; it < T_DIM / 64; ++it) {
        const int buf = it & 1;
        const bool more = (it + 1 < T_DIM / 64);
        if (more) {
            const int qo = (it + 1) * 64;
            qa = *(const bf16x8*)(qbase + (size_t)(qo + qr) * HD + qcg * 8);
            qb = *(const bf16x8*)(qbase + (size_t)(qo + 32 + qr) * HD + qcg * 8);
            if (tid < 64) mlv = m_arr[n * T_DIM + qo + tid];
            else if (tid < 128) mlv = l_arr[n * T_DIM + qo + tid - 64];
        }
        __builtin_amdgcn_s_setprio(1);
#pragma unroll
        for (int qt = 0; qt < 4; ++qt) {
            bf16x8 bq0 = *reinterpret_cast<const bf16x8*>(&Qs[buf][qt * 16 + lr][lg * 8]);
            bf16x8 bq1 = *reinterpret_cast<const bf16x8*>(&Qs[buf][qt * 16 + lr][32 + lg * 8]);
            const float mq = msh[buf][qt * 16 + lr];
            const float lq = lih[buf][qt * 16 + lr];
            f32x4 z;
#pragma unroll
            for (int r = 0; r < 4; ++r) z[r] = -mq;
            z = __builtin_amdgcn_mfma_f32_16x16x32_bf16(ak[0], bq0, z, 0, 0, 0);
            z = __builtin_amdgcn_mfma_f32_16x16x32_bf16(ak[1], bq1, z, 0, 0, 0);
#pragma unroll
            for (int r = 0; r < 4; ++r)
                csum[r] += exp2_fast(z[r]) * lq;
        }
        __builtin_amdgcn_s_setprio(0);
        if (more) {
            *(bf16x8*)&Qs[buf ^ 1][qr][qcg * 8] = qa;
            *(bf16x8*)&Qs[buf ^ 1][32 + qr][qcg * 8] = qb;
            if (tid < 64) msh[buf ^ 1][tid] = mlv;
            else if (tid < 128) lih[buf ^ 1][tid - 64] = 1.0f / mlv;
            __syncthreads();
        }
    }

#pragma unroll
    for (int r = 0; r < 4; ++r) {
        float v = csum[r];
        v += __shfl_xor(v, 1, 16);
        v += __shfl_xor(v, 2, 16);
        v += __shfl_xor(v, 4, 16);
        v += __shfl_xor(v, 8, 16);
        if (lr == 0) {
            const int key = s0 + w * 16 + lg * 4 + r;
            if (key < SP1) avg_out[(size_t)n * SP1 + key] = v * 0.0625f;
        }
    }
}

// ---------------------------------------------------------------------------
extern "C" void kernel_launch(void* const* d_in, const int* in_sizes, int n_in,
                              void* d_out, int out_size, void* d_ws, size_t ws_size,
                              hipStream_t stream)
{
    const float* query   = (const float*)d_in[0];
    const float* key     = (const float*)d_in[1];
    const float* value   = (const float*)d_in[2];
    const float* wq      = (const float*)d_in[3];
    const float* wk      = (const float*)d_in[4];
    const float* wv      = (const float*)d_in[5];
    const float* in_bias = (const float*)d_in[6];
    const float* bias_k  = (const float*)d_in[7];
    const float* bias_v  = (const float*)d_in[8];
    const float* wo      = (const float*)d_in[9];
    const float* out_b   = (const float*)d_in[10];
    float* out = (float*)d_out;

    short* wqb    = (short*)d_ws;                        // [4][1024][1024] bf16
    short* wob    = wqb + (size_t)3 * E_DIM * E_DIM;
    short* qkv_bf = wqb + (size_t)4 * E_DIM * E_DIM;     // [3][8192][1024] bf16
    short* q_h = qkv_bf + 3 * NTOKE;                     // [64][2048][64]
    short* k_h = q_h + (size_t)NH * T_DIM * HD;          // [64][2112][64]
    short* v_h = k_h + (size_t)NH * SPAD * HD;           // [64][2112][64]
    short* o_h = v_h + (size_t)NH * SPAD * HD;           // [64][2048][64]
    float* m_arr = (float*)(o_h + (size_t)NH * T_DIM * HD);
    float* l_arr = m_arr + (size_t)NH * T_DIM;

    const dim3 blk(256);
    hipLaunchKernelGGL(cvt_all, dim3(4096, 4), blk, 0, stream,
                       query, key, value, wq, wk, wv, wo, qkv_bf, wqb,
                       k_h, v_h, bias_k, bias_v);

    hipLaunchKernelGGL(gemm_qkv, dim3(768), dim3(512), 0, stream,
                       qkv_bf, wqb, in_bias, q_h);
    hipLaunchKernelGGL(attn_mfma, dim3(512), dim3(512), 0, stream,
                       q_h, k_h, v_h, o_h, m_arr, l_arr);
    hipLaunchKernelGGL(colsum_mfma, dim3(2112), blk, 0, stream,
                       q_h, k_h, m_arr, l_arr, out + (size_t)T_DIM * B_DIM * E_DIM);
    hipLaunchKernelGGL(gemm_out, dim3(512), blk, 0, stream,
                       o_h, wob, out_b, out);
}

// Round 19
// 275.045 us; speedup vs baseline: 1.0471x; 1.0471x over previous
//
#include <hip/hip_runtime.h>

#define T_DIM 2048
#define B_DIM 4
#define S_DIM 2048
#define E_DIM 1024
#define H_NUM 16
#define HD    64
#define NH    64      // B*H
#define SP1   2049    // S+1 (bias token appended)
#define SPAD  2112    // 33*64, padded key length
#define NCHUNK 33
#define NTOKE ((size_t)T_DIM * B_DIM * E_DIM)   // 8192*1024

typedef short bf16x8 __attribute__((ext_vector_type(8)));
typedef short bf16x4 __attribute__((ext_vector_type(4)));
typedef float f32x4  __attribute__((ext_vector_type(4)));
typedef float f32x16 __attribute__((ext_vector_type(16)));
typedef unsigned int u32;

// log2(e): softmax done in exp2 domain; folded into Q projection scale.
#define QSCALE 0.18033688011112042f   // 0.125 * log2(e)

#if __has_builtin(__builtin_amdgcn_exp2f)
__device__ __forceinline__ float exp2_fast(float x) { return __builtin_amdgcn_exp2f(x); }
#else
__device__ __forceinline__ float exp2_fast(float x) { return __expf(x * 0.6931471805599453f); }
#endif

__device__ __forceinline__ unsigned short f2bf(float x) {
    union { float f; unsigned int u; } v; v.f = x;
    unsigned int r = v.u + 0x7FFFu + ((v.u >> 16) & 1u);   // RNE
    return (unsigned short)(r >> 16);
}

__device__ __forceinline__ u32 cvtpk_bf16(float lo, float hi) {
    u32 r;
    asm("v_cvt_pk_bf16_f32 %0, %1, %2" : "=v"(r) : "v"(lo), "v"(hi));
    return r;
}
__device__ __forceinline__ void plswap(u32& a, u32& b) {
    asm("v_permlane32_swap_b32 %0, %1" : "+v"(a), "+v"(b));
}
__device__ __forceinline__ float max3f(float a, float b, float c) {
    float d;
    asm("v_max3_f32 %0, %1, %2, %3" : "=v"(d) : "v"(a), "v"(b), "v"(c));
    return d;
}

// async global->LDS, 16B per lane (m97 staging primitive)
__device__ __forceinline__ void load_lds16(const void* g, void* l) {
    __builtin_amdgcn_global_load_lds(
        (const __attribute__((address_space(1))) unsigned int*)g,
        (__attribute__((address_space(3))) unsigned int*)l, 16, 0, 0);
}

// ---------------------------------------------------------------------------
// One launch: y=0..2 inputs q|k|v -> bf16; y=3 weights + kv pad fill.
// ---------------------------------------------------------------------------
__global__ __launch_bounds__(256)
void cvt_all(const float* __restrict__ q, const float* __restrict__ k,
             const float* __restrict__ v, const float* __restrict__ w0,
             const float* __restrict__ w1, const float* __restrict__ w2,
             const float* __restrict__ w3, short* __restrict__ indst,
             short* __restrict__ wdst, short* __restrict__ k_h,
             short* __restrict__ v_h, const float* __restrict__ bias_k,
             const float* __restrict__ bias_v)
{
    const int y = blockIdx.y;
    if (y < 3) {
        const float* src = (y == 0) ? q : (y == 1) ? k : v;
        short* d = indst + (size_t)y * NTOKE;
        const size_t i = (size_t)blockIdx.x * 256 + threadIdx.x;
        const float4* s = reinterpret_cast<const float4*>(src) + i * 2;
        float4 a = s[0], b = s[1];
        uint4 o;
        o.x = cvtpk_bf16(a.x, a.y); o.y = cvtpk_bf16(a.z, a.w);
        o.z = cvtpk_bf16(b.x, b.y); o.w = cvtpk_bf16(b.z, b.w);
        *(reinterpret_cast<uint4*>(d) + i) = o;
    } else {
        const size_t gi = (size_t)blockIdx.x * 256 + threadIdx.x;
        const size_t per = (size_t)E_DIM * E_DIM / 8;              // 131072
        if (gi < 4 * per) {
            const int wsel = (int)(gi / per);
            const size_t i = gi % per;
            const float* src = (wsel == 0) ? w0 : (wsel == 1) ? w1 : (wsel == 2) ? w2 : w3;
            short* d = wdst + (size_t)wsel * E_DIM * E_DIM;
            const float4* s = reinterpret_cast<const float4*>(src) + i * 2;
            float4 a = s[0], b = s[1];
            uint4 o;
            o.x = cvtpk_bf16(a.x, a.y); o.y = cvtpk_bf16(a.z, a.w);
            o.z = cvtpk_bf16(b.x, b.y); o.w = cvtpk_bf16(b.z, b.w);
            *(reinterpret_cast<uint4*>(d) + i) = o;
        } else {
            const size_t fi = gi - 4 * per;                        // kv pad fill
            if (fi < (size_t)(SPAD - S_DIM) * NH * HD) {
                const int d   = (int)(fi & 63);
                const int row = (int)((fi >> 6) & 63);
                const int n   = (int)(fi >> 12);
                short bk = 0, bv = 0;
                if (row == 0) {
                    bk = (short)f2bf(bias_k[(n & 15) * HD + d]);
                    bv = (short)f2bf(bias_v[(n & 15) * HD + d]);
                }
                const size_t idx = ((size_t)n * SPAD + S_DIM + row) * HD + d;
                k_h[idx] = bk;
                v_h[idx] = bv;
            }
        }
    }
}

// ---------------------------------------------------------------------------
// QKV GEMM: BK=32 2-phase (best measured form, 32 KB -> 4 blk/CU) upgraded
// with (a) counted-vmcnt depth-2 pipeline: vmcnt(4) keeps next tile's loads
// in flight across raw s_barriers; (b) coalesced epilogue: C staged through
// the freed 32 KB LDS as bf16 [128][128], stored as 16B vectors (8/thread)
// instead of 64 scalar b16 scatters (halves HBM write traffic).
// ---------------------------------------------------------------------------
__global__ __launch_bounds__(256, 4)
void gemm_qkv(const short* __restrict__ Abase, const short* __restrict__ Wall,
              const float* __restrict__ biasAll, short* __restrict__ outp)
{
    __shared__ short smem[16384];       // As[2][128][32] | Bs[2][128][32] = 32 KB
    short* Asb = smem;                  // +buf*4096 shorts
    short* Bsb = smem + 8192;

    const int id = blockIdx.x;                 // 0..1535 (XCD-banded)
    const int xcd = id & 7;
    const int j = id >> 3;                     // 0..191
    const int z = j >> 6;                      // 0..2
    const int jj = j & 63;
    const int bm = xcd * 8 + (jj & 7);
    const int bn = jj >> 3;

    const short* Az = Abase + (size_t)z * NTOKE;
    const short* W  = Wall + (size_t)z * E_DIM * E_DIM;
    const float* bias = biasAll + z * E_DIM;

    const int tid = threadIdx.x;
    const int l = tid & 63, w = tid >> 6;
    const int wr = w >> 1, wc = w & 1;
    const int lr = l & 15, lg = l >> 4;
    const int srow = tid >> 2, scol = (tid & 3) * 8;   // 64 rows / 256 threads

    auto stage = [&](int b, int k0) {
#pragma unroll
        for (int r = 0; r < 2; ++r) {
            const int row = r * 64 + srow;
            load_lds16(Az + (size_t)(bm * 128 + row) * E_DIM + k0 + scol,
                       Asb + b * 4096 + row * 32 + scol);
            load_lds16(W + (size_t)(bn * 128 + row) * E_DIM + k0 + scol,
                       Bsb + b * 4096 + row * 32 + scol);
        }
    };

    stage(0, 0);
    stage(1, 32);

    f32x4 acc[4][4] = {};
    int buf = 0;

    for (int k0 = 0; k0 < E_DIM; k0 += 32) {
        // current tile's 4 loads done; next tile's 4 stay in flight
        if (k0 + 32 < E_DIM)
            asm volatile("s_waitcnt vmcnt(4)" ::: "memory");
        else
            asm volatile("s_waitcnt vmcnt(0)" ::: "memory");
        asm volatile("s_barrier" ::: "memory");
        __builtin_amdgcn_sched_barrier(0);

        __builtin_amdgcn_s_setprio(1);
        bf16x8 af[4], bf[4];
#pragma unroll
        for (int mi = 0; mi < 4; ++mi)
            af[mi] = *reinterpret_cast<const bf16x8*>(
                Asb + buf * 4096 + (wr * 64 + mi * 16 + lr) * 32 + lg * 8);
#pragma unroll
        for (int ni = 0; ni < 4; ++ni)
            bf[ni] = *reinterpret_cast<const bf16x8*>(
                Bsb + buf * 4096 + (wc * 64 + ni * 16 + lr) * 32 + lg * 8);
#pragma unroll
        for (int mi = 0; mi < 4; ++mi)
#pragma unroll
            for (int ni = 0; ni < 4; ++ni)
                acc[mi][ni] = __builtin_amdgcn_mfma_f32_16x16x32_bf16(
                    af[mi], bf[ni], acc[mi][ni], 0, 0, 0);
        __builtin_amdgcn_s_setprio(0);

        asm volatile("s_barrier" ::: "memory");    // all waves done reading buf
        if (k0 + 64 < E_DIM) stage(buf, k0 + 64);
        buf ^= 1;
    }

    // ---- epilogue: C -> LDS bf16 [128][128] -> coalesced 16B stores ----
    // (after final barrier all staging is complete; smem is free)
#pragma unroll
    for (int mi = 0; mi < 4; ++mi)
#pragma unroll
        for (int ni = 0; ni < 4; ++ni) {
            const int colg = bn * 128 + wc * 64 + ni * 16 + lr;
            const float bv = bias[colg];
            const int cl = wc * 64 + ni * 16 + lr;
#pragma unroll
            for (int r = 0; r < 4; ++r) {
                float v = acc[mi][ni][r] + bv;
                if (z == 0) v *= QSCALE;
                const int rowl = wr * 64 + mi * 16 + lg * 4 + r;
                smem[rowl * 128 + cl] = (short)f2bf(v);
            }
        }
    __syncthreads();

    short* ob = outp;
    if (z == 1) ob += (size_t)NH * T_DIM * HD;
    else if (z == 2) ob += (size_t)NH * T_DIM * HD + (size_t)NH * SPAD * HD;
    const int sd = (z == 0) ? T_DIM : SPAD;
#pragma unroll
    for (int p = 0; p < 8; ++p) {
        const int Ls = p * 2048 + tid * 8;       // short index, 16B chunks
        const int rowl = Ls >> 7;                // /128
        const int col  = Ls & 127;
        const int m = bm * 128 + rowl;
        const int seq = m >> 2, b = m & 3;
        const int colg = bn * 128 + col;
        const int head = colg >> 6, d = colg & 63;
        *reinterpret_cast<uint4*>(ob + ((size_t)(b * 16 + head) * sd + seq) * HD + d) =
            *reinterpret_cast<const uint4*>(smem + Ls);
    }
}

// ---------------------------------------------------------------------------
// Out-proj GEMM: 2-phase dbuf BK=64 + XCD-banded grid (round-17 form).
// ---------------------------------------------------------------------------
__global__ __launch_bounds__(256, 2)
void gemm_out(const short* __restrict__ o_h, const short* __restrict__ wob,
              const float* __restrict__ out_b, float* __restrict__ out)
{
    __shared__ short As[2][128][64];
    __shared__ short Bs[2][128][64];

    const int id = blockIdx.x;                 // 0..511
    const int xcd = id & 7;
    const int j = id >> 3;                     // 0..63
    const int bm = xcd * 8 + (j & 7);
    const int bn = j >> 3;

    const int tid = threadIdx.x;
    const int l = tid & 63, w = tid >> 6;
    const int wr = w >> 1, wc = w & 1;
    const int lr = l & 15, lg = l >> 4;
    const int srow = tid >> 3, scol = (tid & 7) * 8;

    auto stage = [&](int b, int k0) {
#pragma unroll
        for (int r = 0; r < 4; ++r) {
            const int row = r * 32 + srow;
            const int m = bm * 128 + row;
            const short* ga = o_h +
                ((size_t)((m & 3) * 16 + (k0 >> 6)) * T_DIM + (m >> 2)) * HD + scol;
            load_lds16(ga, &As[b][row][scol]);
            load_lds16(wob + (size_t)(bn * 128 + row) * E_DIM + k0 + scol, &Bs[b][row][scol]);
        }
    };

    stage(0, 0);
    __syncthreads();

    f32x4 acc[4][4] = {};
    int buf = 0;

    for (int k0 = 0; k0 < E_DIM; k0 += 64) {
        if (k0 + 64 < E_DIM) stage(buf ^ 1, k0 + 64);

        __builtin_amdgcn_s_setprio(1);
#pragma unroll
        for (int c = 0; c < 2; ++c) {
            bf16x8 af[4], bf[4];
#pragma unroll
            for (int mi = 0; mi < 4; ++mi)
                af[mi] = *reinterpret_cast<const bf16x8*>(&As[buf][wr * 64 + mi * 16 + lr][c * 32 + lg * 8]);
#pragma unroll
            for (int ni = 0; ni < 4; ++ni)
                bf[ni] = *reinterpret_cast<const bf16x8*>(&Bs[buf][wc * 64 + ni * 16 + lr][c * 32 + lg * 8]);
#pragma unroll
            for (int mi = 0; mi < 4; ++mi)
#pragma unroll
                for (int ni = 0; ni < 4; ++ni)
                    acc[mi][ni] = __builtin_amdgcn_mfma_f32_16x16x32_bf16(
                        af[mi], bf[ni], acc[mi][ni], 0, 0, 0);
        }
        __builtin_amdgcn_s_setprio(0);
        __syncthreads();
        buf ^= 1;
    }

#pragma unroll
    for (int mi = 0; mi < 4; ++mi)
#pragma unroll
        for (int ni = 0; ni < 4; ++ni) {
            const int colg = bn * 128 + wc * 64 + ni * 16 + lr;
            const float bv = out_b[colg];
#pragma unroll
            for (int r = 0; r < 4; ++r) {
                const int m = bm * 128 + wr * 64 + mi * 16 + lg * 4 + r;
                out[(size_t)m * E_DIM + colg] = acc[mi][ni][r] + bv;
            }
        }
}

// ---------------------------------------------------------------------------
// Swapped 32x32 MFMA flash attention (round-17 form, unchanged).
// ---------------------------------------------------------------------------
__global__ __launch_bounds__(512, 4)
void attn_mfma(const short* __restrict__ q_h, const short* __restrict__ k_h,
               const short* __restrict__ v_h, short* __restrict__ o_h,
               float* __restrict__ m_arr, float* __restrict__ l_arr)
{
    __shared__ short KsD[2][64 * 64];
    __shared__ short VtD[2][64 * 64];

    const int id = blockIdx.x;
    const int xcd = id & 7, slot = id >> 3;        // slot 0..63
    const int n = xcd * 8 + (slot >> 3);
    const int q0 = (slot & 7) * 256;

    const int tid = threadIdx.x, l = tid & 63, w = tid >> 6;   // w 0..7
    const int ql = l & 31;
    const int hi = l >> 5;
    const int qrow = q0 + w * 32 + ql;

    const int krow = tid >> 3, kcg = tid & 7;
    const int kswz = (kcg * 16) ^ ((krow & 7) << 4);
    const int sp = tid & 31, dq = tid >> 5;

    const short* kbase = k_h + (size_t)n * SPAD * HD;
    const short* vbase = v_h + (size_t)n * SPAD * HD;

    bf16x8 aq0, aq1, aq2, aq3;
    {
        const short* qp = q_h + ((size_t)n * T_DIM + qrow) * HD + hi * 8;
        aq0 = *(const bf16x8*)(qp);
        aq1 = *(const bf16x8*)(qp + 16);
        aq2 = *(const bf16x8*)(qp + 32);
        aq3 = *(const bf16x8*)(qp + 48);
    }

    bf16x8 pk  = *(const bf16x8*)(kbase + (size_t)krow * HD + kcg * 8);
    bf16x4 pva = *(const bf16x4*)(vbase + (size_t)(2 * sp) * HD + dq * 4);
    bf16x4 pvb = *(const bf16x4*)(vbase + (size_t)(2 * sp + 1) * HD + dq * 4);
    {
        char* KsB = (char*)KsD[0];
        char* VtB = (char*)VtD[0];
        *(bf16x8*)(KsB + krow * 128 + kswz) = pk;
#pragma unroll
        for (int j = 0; j < 4; ++j) {
            u32 pkd = (u32)(unsigned short)pva[j] | ((u32)(unsigned short)pvb[j] << 16);
            const int d = dq * 4 + j;
            *(u32*)(VtB + d * 128 + ((4 * sp) ^ ((d & 7) << 4))) = pkd;
        }
    }
    __syncthreads();

    float m_run = 0.0f;
    float l_run = 0.0f;
    f32x16 accA, accB;
#pragma unroll
    for (int r = 0; r < 16; ++r) { accA[r] = 0.f; accB[r] = 0.f; }

    for (int kc = 0; kc < NCHUNK; ++kc) {
        const char* KsB = (const char*)KsD[kc & 1];
        const char* VtB = (const char*)VtD[kc & 1];
        const bool more = (kc + 1 < NCHUNK);

        if (more) {
            const int s0n = (kc + 1) * 64;
            pk  = *(const bf16x8*)(kbase + (size_t)(s0n + krow) * HD + kcg * 8);
            pva = *(const bf16x4*)(vbase + (size_t)(s0n + 2 * sp) * HD + dq * 4);
            pvb = *(const bf16x4*)(vbase + (size_t)(s0n + 2 * sp + 1) * HD + dq * 4);
        }

        f32x16 sc0, sc1;
        const float nm = -m_run;
#pragma unroll
        for (int r = 0; r < 16; ++r) { sc0[r] = nm; sc1[r] = nm; }
        __builtin_amdgcn_s_setprio(1);
#pragma unroll
        for (int sl = 0; sl < 4; ++sl) {
            const int cb = ((sl * 32) + hi * 16) ^ ((ql & 7) << 4);
            bf16x8 kf0 = *(const bf16x8*)(KsB + ql * 128 + cb);
            bf16x8 kf1 = *(const bf16x8*)(KsB + (32 + ql) * 128 + cb);
            bf16x8 qf = (sl == 0) ? aq0 : (sl == 1) ? aq1 : (sl == 2) ? aq2 : aq3;
            sc0 = __builtin_amdgcn_mfma_f32_32x32x16_bf16(kf0, qf, sc0, 0, 0, 0);
            sc1 = __builtin_amdgcn_mfma_f32_32x32x16_bf16(kf1, qf, sc1, 0, 0, 0);
        }
        __builtin_amdgcn_s_setprio(0);

        const int s0 = kc * 64;
        if (s0 + 64 > SP1) {
#pragma unroll
            for (int r = 0; r < 16; ++r) {
                const int key = (r & 3) + 8 * (r >> 2) + 4 * hi;
                if (s0 + key >= SP1)      sc0[r] = -1e30f;
                if (s0 + 32 + key >= SP1) sc1[r] = -1e30f;
            }
        }

        // ---- max reduce via v_max3 ----
        float a0 = max3f(sc0[0],  sc0[1],  sc0[2]);
        float a1 = max3f(sc0[3],  sc0[4],  sc0[5]);
        float a2 = max3f(sc0[6],  sc0[7],  sc0[8]);
        float a3 = max3f(sc0[9],  sc0[10], sc0[11]);
        float a4 = max3f(sc0[12], sc0[13], sc0[14]);
        float a5 = max3f(sc0[15], sc1[0],  sc1[1]);
        float a6 = max3f(sc1[2],  sc1[3],  sc1[4]);
        float a7 = max3f(sc1[5],  sc1[6],  sc1[7]);
        float a8 = max3f(sc1[8],  sc1[9],  sc1[10]);
        float a9 = max3f(sc1[11], sc1[12], sc1[13]);
        float aA = fmaxf(sc1[14], sc1[15]);
        float b0 = max3f(a0, a1, a2);
        float b1 = max3f(a3, a4, a5);
        float b2 = max3f(a6, a7, a8);
        float b3 = fmaxf(a9, aA);
        float mxl = fmaxf(max3f(b0, b1, b2), b3);
        const float mx = fmaxf(mxl, __shfl_xor(mxl, 32));
        if (!__all(mx <= 8.0f)) {
            const float sh = fmaxf(mx, 0.0f);
            const float fac = exp2_fast(-sh);
            l_run *= fac;
#pragma unroll
            for (int r = 0; r < 16; ++r) {
                accA[r] *= fac; accB[r] *= fac;
                sc0[r] -= sh;   sc1[r] -= sh;
            }
            m_run += sh;
        }
        float p0[16], p1[16];
#pragma unroll
        for (int r = 0; r < 16; ++r) p0[r] = exp2_fast(sc0[r]);
#pragma unroll
        for (int r = 0; r < 16; ++r) p1[r] = exp2_fast(sc1[r]);
        float sv[16];
#pragma unroll
        for (int r = 0; r < 16; ++r) sv[r] = p0[r] + p1[r];
#pragma unroll
        for (int s = 8; s > 0; s >>= 1)
#pragma unroll
            for (int r = 0; r < s; ++r) sv[r] += sv[r + s];
        l_run += sv[0] + __shfl_xor(sv[0], 32);

        union PF { u32 u[4]; bf16x8 v; };
        PF pf0, pf1, pf2, pf3;
        {
            u32 a0_ = cvtpk_bf16(p0[0], p0[1]),   b0_ = cvtpk_bf16(p0[4], p0[5]);   plswap(a0_, b0_);
            u32 a1_ = cvtpk_bf16(p0[2], p0[3]),   b1_ = cvtpk_bf16(p0[6], p0[7]);   plswap(a1_, b1_);
            u32 a2_ = cvtpk_bf16(p0[8], p0[9]),   b2_ = cvtpk_bf16(p0[12], p0[13]); plswap(a2_, b2_);
            u32 a3_ = cvtpk_bf16(p0[10], p0[11]), b3_ = cvtpk_bf16(p0[14], p0[15]); plswap(a3_, b3_);
            pf0.u[0] = a0_; pf0.u[1] = a1_; pf0.u[2] = b0_; pf0.u[3] = b1_;
            pf1.u[0] = a2_; pf1.u[1] = a3_; pf1.u[2] = b2_; pf1.u[3] = b3_;
            u32 c0_ = cvtpk_bf16(p1[0], p1[1]),   d0_ = cvtpk_bf16(p1[4], p1[5]);   plswap(c0_, d0_);
            u32 c1_ = cvtpk_bf16(p1[2], p1[3]),   d1_ = cvtpk_bf16(p1[6], p1[7]);   plswap(c1_, d1_);
            u32 c2_ = cvtpk_bf16(p1[8], p1[9]),   d2_ = cvtpk_bf16(p1[12], p1[13]); plswap(c2_, d2_);
            u32 c3_ = cvtpk_bf16(p1[10], p1[11]), d3_ = cvtpk_bf16(p1[14], p1[15]); plswap(c3_, d3_);
            pf2.u[0] = c0_; pf2.u[1] = c1_; pf2.u[2] = d0_; pf2.u[3] = d1_;
            pf3.u[0] = c2_; pf3.u[1] = c3_; pf3.u[2] = d2_; pf3.u[3] = d3_;
        }

        __builtin_amdgcn_s_setprio(1);
#pragma unroll
        for (int ksl = 0; ksl < 4; ++ksl) {
            const int cb = ((ksl * 32) + hi * 16) ^ ((ql & 7) << 4);
            bf16x8 vf0 = *(const bf16x8*)(VtB + ql * 128 + cb);
            bf16x8 vf1 = *(const bf16x8*)(VtB + (32 + ql) * 128 + cb);
            const bf16x8 pv = (ksl == 0) ? pf0.v : (ksl == 1) ? pf1.v : (ksl == 2) ? pf2.v : pf3.v;
            accA = __builtin_amdgcn_mfma_f32_32x32x16_bf16(vf0, pv, accA, 0, 0, 0);
            accB = __builtin_amdgcn_mfma_f32_32x32x16_bf16(vf1, pv, accB, 0, 0, 0);
        }
        __builtin_amdgcn_s_setprio(0);

        if (more) {
            char* KsN = (char*)KsD[(kc & 1) ^ 1];
            char* VtN = (char*)VtD[(kc & 1) ^ 1];
            *(bf16x8*)(KsN + krow * 128 + kswz) = pk;
#pragma unroll
            for (int j = 0; j < 4; ++j) {
                u32 pkd = (u32)(unsigned short)pva[j] | ((u32)(unsigned short)pvb[j] << 16);
                const int d = dq * 4 + j;
                *(u32*)(VtN + d * 128 + ((4 * sp) ^ ((d & 7) << 4))) = pkd;
            }
            __syncthreads();
        }
    }

    const float il = 1.0f / l_run;
    short* orow = o_h + ((size_t)n * T_DIM + qrow) * HD;
#pragma unroll
    for (int rq = 0; rq < 4; ++rq) {
        uint2 st;
        st.x = cvtpk_bf16(accA[rq * 4 + 0] * il, accA[rq * 4 + 1] * il);
        st.y = cvtpk_bf16(accA[rq * 4 + 2] * il, accA[rq * 4 + 3] * il);
        *(uint2*)(orow + rq * 8 + hi * 4) = st;
        uint2 st2;
        st2.x = cvtpk_bf16(accB[rq * 4 + 0] * il, accB[rq * 4 + 1] * il);
        st2.y = cvtpk_bf16(accB[rq * 4 + 2] * il, accB[rq * 4 + 3] * il);
        *(uint2*)(orow + 32 + rq * 8 + hi * 4) = st2;
    }
    if (hi == 0) {
        m_arr[n * T_DIM + qrow] = m_run;
        l_arr[n * T_DIM + qrow] = l_run;
    }
}

// ---------------------------------------------------------------------------
// avg_weights: standalone, -mq in acc init (unchanged).
// ---------------------------------------------------------------------------
__global__ __launch_bounds__(256)
void colsum_mfma(const short* __restrict__ q_h, const short* __restrict__ k_h,
                 const float* __restrict__ m_arr, const float* __restrict__ l_arr,
                 float* __restrict__ avg_out)
{
    __shared__ short Qs[2][64][72];
    __shared__ float msh[2][64];
    __shared__ float lih[2][64];

    const int id = blockIdx.x;
    const int xcd = id & 7, slot = id >> 3;        // slot 0..263
    const int n = xcd * 8 + slot / 33;
    const int s0 = (slot % 33) * 64;

    const int tid = threadIdx.x, l = tid & 63, w = tid >> 6;
    const int lr = l & 15, lg = l >> 4;
    const int qr = tid >> 3, qcg = tid & 7;

    const short* qbase = q_h + (size_t)n * T_DIM * HD;

    bf16x8 ak[2];
#pragma unroll
    for (int c = 0; c < 2; ++c)
        ak[c] = *reinterpret_cast<const bf16x8*>(
            k_h + ((size_t)n * SPAD + s0 + w * 16 + lr) * HD + c * 32 + lg * 8);

    bf16x8 qa = *(const bf16x8*)(qbase + (size_t)qr * HD + qcg * 8);
    bf16x8 qb = *(const bf16x8*)(qbase + (size_t)(32 + qr) * HD + qcg * 8);
    float mlv = 0.f;
    if (tid < 64) mlv = m_arr[n * T_DIM + tid];
    else if (tid < 128) mlv = l_arr[n * T_DIM + tid - 64];
    *(bf16x8*)&Qs[0][qr][qcg * 8] = qa;
    *(bf16x8*)&Qs[0][32 + qr][qcg * 8] = qb;
    if (tid < 64) msh[0][tid] = mlv;
    else if (tid < 128) lih[0][tid - 64] = 1.0f / mlv;
    __syncthreads();

    float csum[4] = {0.f, 0.f, 0.f, 0.f};

    for (int it = 0; it < T_DIM / 64; ++it) {
        const int buf = it & 1;
        const bool more = (it + 1 < T_DIM / 64);
        if (more) {
            const int qo = (it + 1) * 64;
            qa = *(const bf16x8*)(qbase + (size_t)(qo + qr) * HD + qcg * 8);
            qb = *(const bf16x8*)(qbase + (size_t)(qo + 32 + qr) * HD + qcg * 8);
            if (tid < 64) mlv = m_arr[n * T_DIM + qo + tid];
            else if (tid < 128) mlv = l_arr[n * T_DIM + qo + tid - 64];
        }
        __builtin_amdgcn_s_setprio(1);
#pragma unroll
        for (int qt = 0; qt < 4; ++qt) {
            bf16x8 bq0 = *reinterpret_cast<const bf16x8*>(&Qs[buf][qt * 16 + lr][lg * 8]);
            bf16x8 bq1 = *reinterpret_cast<const bf16x8*>(&Qs[buf][qt * 16 + lr][32 + lg * 8]);
            const float mq = msh[buf][qt * 16 + lr];
            const float lq = lih[buf][qt * 16 + lr];
            f32x4 z;
#pragma unroll
            for (int r = 0; r < 4; ++r) z[r] = -mq;
            z = __builtin_amdgcn_mfma_f32_16x16x32_bf16(ak[0], bq0, z, 0, 0, 0);
            z = __builtin_amdgcn_mfma_f32_16x16x32_bf16(ak[1], bq1, z, 0, 0, 0);
#pragma unroll
            for (int r = 0; r < 4; ++r)
                csum[r] += exp2_fast(z[r]) * lq;
        }
        __builtin_amdgcn_s_setprio(0);
        if (more) {
            *(bf16x8*)&Qs[buf ^ 1][qr][qcg * 8] = qa;
            *(bf16x8*)&Qs[buf ^ 1][32 + qr][qcg * 8] = qb;
            if (tid < 64) msh[buf ^ 1][tid] = mlv;
            else if (tid < 128) lih[buf ^ 1][tid - 64] = 1.0f / mlv;
            __syncthreads();
        }
    }

#pragma unroll
    for (int r = 0; r < 4; ++r) {
        float v = csum[r];
        v += __shfl_xor(v, 1, 16);
        v += __shfl_xor(v, 2, 16);
        v += __shfl_xor(v, 4, 16);
        v += __shfl_xor(v, 8, 16);
        if (lr == 0) {
            const int key = s0 + w * 16 + lg * 4 + r;
            if (key < SP1) avg_out[(size_t)n * SP1 + key] = v * 0.0625f;
        }
    }
}

// ---------------------------------------------------------------------------
extern "C" void kernel_launch(void* const* d_in, const int* in_sizes, int n_in,
                              void* d_out, int out_size, void* d_ws, size_t ws_size,
                              hipStream_t stream)
{
    const float* query   = (const float*)d_in[0];
    const float* key     = (const float*)d_in[1];
    const float* value   = (const float*)d_in[2];
    const float* wq      = (const float*)d_in[3];
    const float* wk      = (const float*)d_in[4];
    const float* wv      = (const float*)d_in[5];
    const float* in_bias = (const float*)d_in[6];
    const float* bias_k  = (const float*)d_in[7];
    const float* bias_v  = (const float*)d_in[8];
    const float* wo      = (const float*)d_in[9];
    const float* out_b   = (const float*)d_in[10];
    float* out = (float*)d_out;

    short* wqb    = (short*)d_ws;                        // [4][1024][1024] bf16
    short* wob    = wqb + (size_t)3 * E_DIM * E_DIM;
    short* qkv_bf = wqb + (size_t)4 * E_DIM * E_DIM;     // [3][8192][1024] bf16
    short* q_h = qkv_bf + 3 * NTOKE;                     // [64][2048][64]
    short* k_h = q_h + (size_t)NH * T_DIM * HD;          // [64][2112][64]
    short* v_h = k_h + (size_t)NH * SPAD * HD;           // [64][2112][64]
    short* o_h = v_h + (size_t)NH * SPAD * HD;           // [64][2048][64]
    float* m_arr = (float*)(o_h + (size_t)NH * T_DIM * HD);
    float* l_arr = m_arr + (size_t)NH * T_DIM;

    const dim3 blk(256);
    hipLaunchKernelGGL(cvt_all, dim3(4096, 4), blk, 0, stream,
                       query, key, value, wq, wk, wv, wo, qkv_bf, wqb,
                       k_h, v_h, bias_k, bias_v);

    hipLaunchKernelGGL(gemm_qkv, dim3(1536), blk, 0, stream,
                       qkv_bf, wqb, in_bias, q_h);
    hipLaunchKernelGGL(attn_mfma, dim3(512), dim3(512), 0, stream,
                       q_h, k_h, v_h, o_h, m_arr, l_arr);
    hipLaunchKernelGGL(colsum_mfma, dim3(2112), blk, 0, stream,
                       q_h, k_h, m_arr, l_arr, out + (size_t)T_DIM * B_DIM * E_DIM);
    hipLaunchKernelGGL(gemm_out, dim3(512), blk, 0, stream,
                       o_h, wob, out_b, out);
}